// Round 4
// baseline (726.944 us; speedup 1.0000x reference)
//
#include <hip/hip_runtime.h>
#include <hip/hip_bf16.h>

// DecoupledMVRowSelfAttn fused implementation (round-3 resubmit; R1-R3 were
// broker acquisition timeouts — kernel has never run).
// Pipeline:
//  1) k_conv: hidden/ref f32 -> bf16
//  2) k_wt:   12 weights f32 (K,N) -> bf16 transposed (N,K); Wq* scaled by 0.125
//  3) k_gemm<0>: QKV GEMM  (M=6144,N=8960,K=1280) -> QKV5 rowmajor + VT_base/VT_mv transposed
//  4) k_gemm<1>: refKV GEMM (N=2560) -> KREF rowmajor + VT_ref transposed
//  5) k_flash<0/1/2>: flash attention (base / multiview / ref) -> out_cat bf16 (6144x3840)
//  6) k_gemm<2>: out_cat @ WT_out (K=3840) + biases + residual -> d_out f32
// Requires ws_size >= ~213 MB.

typedef __bf16 bf16;
typedef __bf16 bf16x8 __attribute__((ext_vector_type(8)));
typedef float f32x4 __attribute__((ext_vector_type(4)));

#define LOG2E 1.44269504088896340f

__device__ __forceinline__ unsigned pk2(float a, float b){
  unsigned short x = __builtin_bit_cast(unsigned short, (bf16)a);
  unsigned short y = __builtin_bit_cast(unsigned short, (bf16)b);
  return (unsigned)x | ((unsigned)y << 16);
}

__device__ __forceinline__ void glds16(const void* g, void* l){
  __builtin_amdgcn_global_load_lds((const __attribute__((address_space(1))) void*)g,
                                   (__attribute__((address_space(3))) void*)l, 16, 0, 0);
}

// ---------------- convert hidden/ref to bf16 ----------------
__global__ void __launch_bounds__(256) k_conv(const float* __restrict__ h,
                                              const float* __restrict__ r,
                                              bf16* __restrict__ xb, bf16* __restrict__ rb)
{
  size_t i = (size_t)blockIdx.x*256 + threadIdx.x;   // 6144*1280/4 groups, exact grid
  float4 a = ((const float4*)h)[i];
  uint2 u; u.x = pk2(a.x, a.y); u.y = pk2(a.z, a.w);
  ((uint2*)xb)[i] = u;
  float4 b = ((const float4*)r)[i];
  uint2 v; v.x = pk2(b.x, b.y); v.y = pk2(b.z, b.w);
  ((uint2*)rb)[i] = v;
}

// ---------------- weight transpose+convert ----------------
// z order: 0 Wq,1 Wk,2 Wv,3 Wq_mv,4 Wk_mv,5 Wv_mv,6 Wq_ref -> wt_qkv rows z*1280
//          7 Wk_ref,8 Wv_ref -> wt_ref ; 9 Wout,10 Wout_mv,11 Wout_ref -> wt_out cols (z-9)*1280
struct W12 { const float* p[12]; };

__global__ void __launch_bounds__(256) k_wt(W12 srcs, bf16* __restrict__ wt_qkv,
                                            bf16* __restrict__ wt_ref, bf16* __restrict__ wt_out)
{
  int z = blockIdx.z;
  const float* src = srcs.p[z];
  float scale = (z==0 || z==3 || z==6) ? 0.125f : 1.0f;   // fold 1/sqrt(64) into Wq*
  bf16* dst; int ldd;
  if (z < 7)      { dst = wt_qkv + (size_t)z*1280*1280; ldd = 1280; }
  else if (z < 9) { dst = wt_ref + (size_t)(z-7)*1280*1280; ldd = 1280; }
  else            { dst = wt_out + (size_t)(z-9)*1280; ldd = 3840; }

  __shared__ float tile[32][33];
  int tx = threadIdx.x & 31, ty = threadIdx.x >> 5;
  int r0 = blockIdx.y*32, c0 = blockIdx.x*32;
  #pragma unroll
  for (int i=0;i<32;i+=8)
    tile[ty+i][tx] = src[(size_t)(r0+ty+i)*1280 + c0+tx] * scale;
  __syncthreads();
  #pragma unroll
  for (int i=0;i<32;i+=8)
    dst[(size_t)(c0+ty+i)*ldd + r0+tx] = (bf16)tile[tx][ty+i];
}

// ---------------- GEMM: C = A(MxK) * BT(NxK)^T ----------------
// 128x128 tile, BK=64, 4 waves (each 64x64), 16x16x32 bf16 MFMA.
// EPI 0: QKV routing (Q/K/Qmv/Kmv/Qref rowmajor -> Crm ld 6400; V->VT1[bs][h][d][1024]; Vmv->VT2[h][d][6144])
// EPI 1: refKV routing (Kref rowmajor ld 1280; Vref->VT1)
// EPI 2: f32 out + (b0+b1+b2)[col] + resid[row][col]
template<int EPI>
__global__ void __launch_bounds__(256) k_gemm(const bf16* __restrict__ A, const bf16* __restrict__ BT,
            int K, int lda, int ldb,
            bf16* __restrict__ Crm, int ldc,
            bf16* __restrict__ VT1, bf16* __restrict__ VT2,
            const float* __restrict__ resid,
            const float* __restrict__ b0, const float* __restrict__ b1, const float* __restrict__ b2,
            float* __restrict__ outF)
{
  __shared__ bf16 As[128*64];
  __shared__ bf16 Bs[128*64];
  const int tid = threadIdx.x;
  const int w = tid >> 6, l = tid & 63;
  const int c = l & 15, g = l >> 4;
  const int m0 = blockIdx.y * 128, n0 = blockIdx.x * 128;
  const int wr = (w >> 1) * 64, wc = (w & 1) * 64;

  f32x4 acc[4][4];
  #pragma unroll
  for (int i=0;i<4;i++)
    #pragma unroll
    for (int j=0;j<4;j++) acc[i][j] = (f32x4){0.f,0.f,0.f,0.f};

  for (int k0 = 0; k0 < K; k0 += 64){
    __syncthreads();
    #pragma unroll
    for (int j=0;j<4;j++){
      int chunk = j*256 + tid;
      int row = chunk >> 3, cc = chunk & 7;
      int sc8 = ((cc ^ (row & 7)) << 3);          // pre-swizzled global source (rule 21)
      glds16(A  + (size_t)(m0+row)*lda + k0 + sc8, (char*)As + ((size_t)(j*256 + (w<<6)) << 4));
      glds16(BT + (size_t)(n0+row)*ldb + k0 + sc8, (char*)Bs + ((size_t)(j*256 + (w<<6)) << 4));
    }
    __syncthreads();
    #pragma unroll
    for (int kk=0;kk<2;kk++){
      bf16x8 af[4], bfr[4];
      #pragma unroll
      for (int m=0;m<4;m++){
        int row = wr + m*16 + c;
        af[m] = *(const bf16x8*)((const char*)As + row*128 + ((((kk<<2)+g) ^ (row&7)) << 4));
      }
      #pragma unroll
      for (int n=0;n<4;n++){
        int row = wc + n*16 + c;
        bfr[n] = *(const bf16x8*)((const char*)Bs + row*128 + ((((kk<<2)+g) ^ (row&7)) << 4));
      }
      #pragma unroll
      for (int m=0;m<4;m++)
        #pragma unroll
        for (int n=0;n<4;n++)
          acc[m][n] = __builtin_amdgcn_mfma_f32_16x16x32_bf16(af[m], bfr[n], acc[m][n], 0,0,0);
    }
  }

  if (EPI == 2){
    #pragma unroll
    for (int nf=0;nf<4;nf++){
      int col = n0 + wc + nf*16 + c;
      float bias = b0[col] + b1[col] + b2[col];
      #pragma unroll
      for (int mf=0;mf<4;mf++)
        #pragma unroll
        for (int r=0;r<4;r++){
          int row = m0 + wr + mf*16 + (g<<2) + r;
          size_t idx = (size_t)row*1280 + col;
          outF[idx] = acc[mf][nf][r] + bias + resid[idx];
        }
    }
    return;
  }

  int reg = n0 / 1280;
  bool vt = (EPI==0) ? (reg==2 || reg==5) : (reg==1);
  if (!vt){
    int colbase = (EPI==0) ? (n0 - ((reg>=3)?1280:0) - ((reg>=6)?1280:0)) : n0;
    #pragma unroll
    for (int mf=0;mf<4;mf++)
      #pragma unroll
      for (int nf=0;nf<4;nf++)
        #pragma unroll
        for (int r=0;r<4;r++){
          int row = m0 + wr + mf*16 + (g<<2) + r;
          Crm[(size_t)row*ldc + colbase + wc + nf*16 + c] = (bf16)acc[mf][nf][r];
        }
  } else {
    bf16* vdst; int cm0; bool mv = false;
    if (EPI==0){
      if (reg==2){ vdst = VT1; cm0 = n0 - 2560; }
      else       { vdst = VT2; cm0 = n0 - 6400; mv = true; }
    } else       { vdst = VT1; cm0 = n0 - 1280; }
    #pragma unroll
    for (int nf=0;nf<4;nf++){
      int cm = cm0 + wc + nf*16 + c;
      int hh = cm >> 6, dd = cm & 63;
      #pragma unroll
      for (int mf=0;mf<4;mf++){
        int tok0 = m0 + wr + mf*16 + (g<<2);     // 4-aligned, stays within one image
        size_t addr;
        if (mv) addr = ((size_t)(hh*64 + dd))*6144 + tok0;
        else    addr = ((size_t)(((tok0>>10)*20 + hh)*64 + dd))*1024 + (size_t)(tok0 & 1023);
        uint2 v; v.x = pk2(acc[mf][nf][0], acc[mf][nf][1]); v.y = pk2(acc[mf][nf][2], acc[mf][nf][3]);
        *(uint2*)((char*)vdst + addr*2) = v;
      }
    }
  }
}

// ---------------- flash attention ----------------
// MODE 0 base, 1 multiview, 2 ref. 4 waves, Q-tile 128 (32 q/wave), KV-tile 64.
// S^T = mfma(K,Q): lane holds ST[key=m*16+4g+r][q=w*32+nf*16+c]. Softmax: in-lane + shfl_xor(16,32).
// P -> swizzled LDS -> PV: O = mfma(P, VT-rows).
template<int MODE>
__global__ void __launch_bounds__(256) k_flash(const bf16* __restrict__ qkv5, const bf16* __restrict__ kref,
              const bf16* __restrict__ vt_base, const bf16* __restrict__ vt_mv,
              const bf16* __restrict__ vt_ref, bf16* __restrict__ outcat)
{
  __shared__ bf16 Ks[64*64];
  __shared__ bf16 VTs[64*64];
  __shared__ bf16 Pl[128*64];
  __shared__ float scl[128];
  __shared__ float lsum[128];

  const int tid = threadIdx.x;
  const int w = tid >> 6, l = tid & 63;
  const int c = l & 15, g = l >> 4;
  const int qt = blockIdx.x, grp = blockIdx.y;

  int hh, ldk, bidx = 0, iv = 0, NKT, Lq, ocol;
  const bf16 *Qb, *Kb, *Vb;
  if (MODE==0){
    bidx = grp/20; hh = grp%20;
    Qb = qkv5 + (size_t)hh*64;
    Kb = qkv5 + 1280 + (size_t)hh*64; ldk = 6400;
    Vb = vt_base + ((size_t)(bidx*20 + hh)*64)*1024;
    NKT = 16; Lq = 1024; ocol = hh*64;
  } else if (MODE==1){
    iv = grp/20; hh = grp%20;     // iv = image row (0..31)
    Qb = qkv5 + 2560 + (size_t)hh*64;
    Kb = qkv5 + 3840 + (size_t)hh*64; ldk = 6400;
    Vb = vt_mv + ((size_t)hh*64)*6144;
    NKT = 3; Lq = 192; ocol = 1280 + hh*64;
  } else {
    bidx = grp/20; hh = grp%20;
    Qb = qkv5 + 5120 + (size_t)hh*64;
    Kb = kref + (size_t)hh*64; ldk = 1280;
    Vb = vt_ref + ((size_t)(bidx*20 + hh)*64)*1024;
    NKT = 16; Lq = 1024; ocol = 2560 + hh*64;
  }

  // Q fragments in registers (1/sqrt(d) pre-folded into Wq)
  bf16x8 qf[2][2];
  #pragma unroll
  for (int nf=0;nf<2;nf++){
    int qa = qt*128 + w*32 + nf*16 + c;
    if (qa > Lq-1) qa = Lq-1;
    int tq = (MODE==1) ? (((qa>>5)<<10) + iv*32 + (qa&31)) : ((bidx<<10) + qa);
    #pragma unroll
    for (int kk=0;kk<2;kk++)
      qf[nf][kk] = *(const bf16x8*)(Qb + (size_t)tq*6400 + kk*32 + g*8);
  }

  float mrow[2] = {-1e30f, -1e30f};
  float lrow[2] = {0.f, 0.f};
  f32x4 oacc[2][4];
  #pragma unroll
  for (int i=0;i<2;i++)
    #pragma unroll
    for (int j=0;j<4;j++) oacc[i][j] = (f32x4){0.f,0.f,0.f,0.f};

  for (int kt=0; kt<NKT; ++kt){
    __syncthreads();
    #pragma unroll
    for (int j=0;j<2;j++){                         // stage K tile (gathered rows, pre-swizzled)
      int lc = j*256 + tid;
      int row = lc >> 3, cc = lc & 7;
      int sc8 = ((cc ^ (row&7)) << 3);
      int ka = kt*64 + row;
      int tk = (MODE==1) ? (((ka>>5)<<10) + iv*32 + (ka&31)) : ((bidx<<10) + ka);
      glds16(Kb + (size_t)tk*ldk + sc8, (char*)Ks + ((size_t)(j*256 + (w<<6))<<4));
    }
    #pragma unroll
    for (int j=0;j<2;j++){                         // stage VT tile
      int lc = j*256 + tid;
      int dd = lc >> 3, cc = lc & 7;
      int k8 = kt*64 + ((cc ^ (dd&7)) << 3);
      const bf16* src;
      if (MODE==1) src = Vb + (size_t)dd*6144 + ((k8>>5)<<10) + iv*32 + (k8&31);
      else         src = Vb + (size_t)dd*1024 + k8;
      glds16(src, (char*)VTs + ((size_t)(j*256 + (w<<6))<<4));
    }
    __syncthreads();

    // S^T = K * Q^T
    f32x4 st[4][2];
    #pragma unroll
    for (int m=0;m<4;m++)
      #pragma unroll
      for (int nf=0;nf<2;nf++) st[m][nf] = (f32x4){0.f,0.f,0.f,0.f};
    #pragma unroll
    for (int kk=0;kk<2;kk++){
      bf16x8 kf[4];
      #pragma unroll
      for (int m=0;m<4;m++){
        int row = m*16 + c;
        kf[m] = *(const bf16x8*)((const char*)Ks + row*128 + ((((kk<<2)+g)^(row&7))<<4));
      }
      #pragma unroll
      for (int m=0;m<4;m++)
        #pragma unroll
        for (int nf=0;nf<2;nf++)
          st[m][nf] = __builtin_amdgcn_mfma_f32_16x16x32_bf16(kf[m], qf[nf][kk], st[m][nf], 0,0,0);
    }

    // online softmax (per q-row = per lane&15 within nf)
    #pragma unroll
    for (int nf=0;nf<2;nf++){
      float pm = st[0][nf][0];
      #pragma unroll
      for (int m=0;m<4;m++)
        #pragma unroll
        for (int r=0;r<4;r++) pm = fmaxf(pm, st[m][nf][r]);
      pm = fmaxf(pm, __shfl_xor(pm, 16));
      pm = fmaxf(pm, __shfl_xor(pm, 32));
      float mnew = fmaxf(mrow[nf], pm);
      float sc = exp2f((mrow[nf] - mnew) * LOG2E);
      float ps = 0.f;
      int qlds = w*32 + nf*16 + c;
      #pragma unroll
      for (int m=0;m<4;m++){
        float p0 = exp2f((st[m][nf][0]-mnew)*LOG2E);
        float p1 = exp2f((st[m][nf][1]-mnew)*LOG2E);
        float p2 = exp2f((st[m][nf][2]-mnew)*LOG2E);
        float p3 = exp2f((st[m][nf][3]-mnew)*LOG2E);
        ps += p0+p1+p2+p3;
        uint2 pv; pv.x = pk2(p0,p1); pv.y = pk2(p2,p3);
        int ci = ((m*2 + (g>>1)) ^ (qlds&7));
        *(uint2*)((char*)Pl + qlds*128 + (ci<<4) + ((g&1)<<3)) = pv;   // P[q][key=m*16+4g..+3]
      }
      ps += __shfl_xor(ps, 16);
      ps += __shfl_xor(ps, 32);
      lrow[nf] = lrow[nf]*sc + ps;
      mrow[nf] = mnew;
      scl[qlds] = sc;
    }
    // rescale O accumulators (stats lane-map differs from O lane-map -> via LDS broadcast)
    #pragma unroll
    for (int mf=0;mf<2;mf++)
      #pragma unroll
      for (int r=0;r<4;r++){
        float s = scl[w*32 + mf*16 + (g<<2) + r];
        #pragma unroll
        for (int nd=0;nd<4;nd++) oacc[mf][nd][r] *= s;
      }
    // PV: O += P * V   (A = P rows from LDS, B = V^T rows from LDS)
    #pragma unroll
    for (int ks=0;ks<2;ks++){
      bf16x8 pf[2], vf[4];
      #pragma unroll
      for (int mf=0;mf<2;mf++){
        int q = w*32 + mf*16 + c;
        pf[mf] = *(const bf16x8*)((const char*)Pl + q*128 + ((((ks<<2)+g)^(q&7))<<4));
      }
      #pragma unroll
      for (int nd=0;nd<4;nd++){
        int row = nd*16 + c;
        vf[nd] = *(const bf16x8*)((const char*)VTs + row*128 + ((((ks<<2)+g)^(row&7))<<4));
      }
      #pragma unroll
      for (int mf=0;mf<2;mf++)
        #pragma unroll
        for (int nd=0;nd<4;nd++)
          oacc[mf][nd] = __builtin_amdgcn_mfma_f32_16x16x32_bf16(pf[mf], vf[nd], oacc[mf][nd], 0,0,0);
    }
  }

  #pragma unroll
  for (int nf=0;nf<2;nf++) lsum[w*32 + nf*16 + c] = lrow[nf];
  #pragma unroll
  for (int mf=0;mf<2;mf++)
    #pragma unroll
    for (int r=0;r<4;r++){
      int qloc = w*32 + mf*16 + (g<<2) + r;
      float inv = 1.f / lsum[qloc];
      int qa = qt*128 + qloc;
      if (qa < Lq){
        int tq = (MODE==1) ? (((qa>>5)<<10) + iv*32 + (qa&31)) : ((bidx<<10) + qa);
        #pragma unroll
        for (int nd=0;nd<4;nd++)
          outcat[(size_t)tq*3840 + ocol + nd*16 + c] = (bf16)(oacc[mf][nd][r] * inv);
      }
    }
}

// ---------------- launcher ----------------
extern "C" void kernel_launch(void* const* d_in, const int* in_sizes, int n_in,
                              void* d_out, int out_size, void* d_ws, size_t ws_size,
                              hipStream_t stream)
{
  (void)in_sizes; (void)n_in; (void)out_size; (void)ws_size;
  const float* hs  = (const float*)d_in[0];
  const float* rhs = (const float*)d_in[1];
  const float* bq  = (const float*)d_in[6];    // bout
  const float* bm  = (const float*)d_in[11];   // bout_mv
  const float* br  = (const float*)d_in[16];   // bout_ref

  char* ws = (char*)d_ws;
  size_t off = 0;
  auto alloc = [&](size_t bytes){ size_t a = off; off += (bytes + 255) & ~(size_t)255; return a; };
  size_t oXBF   = alloc((size_t)6144*1280*2);
  size_t oRBF   = alloc((size_t)6144*1280*2);
  size_t oWTQKV = alloc((size_t)8960*1280*2);
  size_t oWTREF = alloc((size_t)2560*1280*2);
  size_t oWTOUT = alloc((size_t)1280*3840*2);
  size_t oQKV5  = alloc((size_t)6144*6400*2);
  size_t oKREF  = alloc((size_t)6144*1280*2);
  size_t oVTB   = alloc((size_t)6*20*64*1024*2);
  size_t oVTM   = alloc((size_t)20*64*6144*2);
  size_t oVTR   = alloc((size_t)6*20*64*1024*2);
  size_t oOUT   = oXBF;   // out_cat (47.2MB) aliases XBF+RBF+WTQKV (54.4MB), dead by then

  bf16* XBF   = (bf16*)(ws + oXBF);
  bf16* RBF   = (bf16*)(ws + oRBF);
  bf16* WTQKV = (bf16*)(ws + oWTQKV);
  bf16* WTREF = (bf16*)(ws + oWTREF);
  bf16* WTOUT = (bf16*)(ws + oWTOUT);
  bf16* QKV5  = (bf16*)(ws + oQKV5);
  bf16* KREF  = (bf16*)(ws + oKREF);
  bf16* VTB   = (bf16*)(ws + oVTB);
  bf16* VTM   = (bf16*)(ws + oVTM);
  bf16* VTR   = (bf16*)(ws + oVTR);
  bf16* OUTC  = (bf16*)(ws + oOUT);

  k_conv<<<7680, 256, 0, stream>>>(hs, rhs, XBF, RBF);

  W12 wsrc;
  wsrc.p[0]=(const float*)d_in[2];  wsrc.p[1]=(const float*)d_in[3];  wsrc.p[2]=(const float*)d_in[4];
  wsrc.p[3]=(const float*)d_in[7];  wsrc.p[4]=(const float*)d_in[8];  wsrc.p[5]=(const float*)d_in[9];
  wsrc.p[6]=(const float*)d_in[12]; wsrc.p[7]=(const float*)d_in[13]; wsrc.p[8]=(const float*)d_in[14];
  wsrc.p[9]=(const float*)d_in[5];  wsrc.p[10]=(const float*)d_in[10]; wsrc.p[11]=(const float*)d_in[15];
  k_wt<<<dim3(40,40,12), 256, 0, stream>>>(wsrc, WTQKV, WTREF, WTOUT);

  k_gemm<0><<<dim3(70,48), 256, 0, stream>>>(XBF, WTQKV, 1280, 1280, 1280,
      QKV5, 6400, VTB, VTM, nullptr, nullptr, nullptr, nullptr, nullptr);
  k_gemm<1><<<dim3(20,48), 256, 0, stream>>>(RBF, WTREF, 1280, 1280, 1280,
      KREF, 1280, VTR, nullptr, nullptr, nullptr, nullptr, nullptr, nullptr);

  k_flash<0><<<dim3(8,120), 256, 0, stream>>>(QKV5, KREF, VTB, VTM, VTR, OUTC);
  k_flash<1><<<dim3(2,640), 256, 0, stream>>>(QKV5, KREF, VTB, VTM, VTR, OUTC);
  k_flash<2><<<dim3(8,120), 256, 0, stream>>>(QKV5, KREF, VTB, VTM, VTR, OUTC);

  k_gemm<2><<<dim3(10,48), 256, 0, stream>>>(OUTC, WTOUT, 3840, 3840, 3840,
      nullptr, 0, nullptr, nullptr, hs, bq, bm, br, (float*)d_out);
}

// Round 5
// 714.338 us; speedup vs baseline: 1.0176x; 1.0176x over previous
//
#include <hip/hip_runtime.h>
#include <hip/hip_bf16.h>

// DecoupledMVRowSelfAttn fused implementation, round 5.
// R4 baseline: 727us total, k_gemm<0> = 185us @ 869 TF (m97-structure ceiling,
// MfmaUtil 34%, 0 bank conflicts). This round: QKV + refKV GEMMs moved to a
// 256x256 8-phase counted-vmcnt schedule (T2+T3+T4+T5); quarters staged
// round-robin (AX,BX,BY,AY) so vmcnt(4) certifies exactly what the next
// phase's ds_reads need — never drains to 0 in the main loop.
// gemm<2> (K=3840, only 120 blocks at 256^2) stays on the 128^2 kernel.
// Flash kernels unchanged (no timing evidence yet).

typedef __bf16 bf16;
typedef __bf16 bf16x8 __attribute__((ext_vector_type(8)));
typedef float f32x4 __attribute__((ext_vector_type(4)));

#define LOG2E 1.44269504088896340f

__device__ __forceinline__ unsigned pk2(float a, float b){
  unsigned short x = __builtin_bit_cast(unsigned short, (bf16)a);
  unsigned short y = __builtin_bit_cast(unsigned short, (bf16)b);
  return (unsigned)x | ((unsigned)y << 16);
}

__device__ __forceinline__ void glds16(const void* g, void* l){
  __builtin_amdgcn_global_load_lds((const __attribute__((address_space(1))) void*)g,
                                   (__attribute__((address_space(3))) void*)l, 16, 0, 0);
}

// ---------------- convert hidden/ref to bf16 ----------------
__global__ void __launch_bounds__(256) k_conv(const float* __restrict__ h,
                                              const float* __restrict__ r,
                                              bf16* __restrict__ xb, bf16* __restrict__ rb)
{
  size_t i = (size_t)blockIdx.x*256 + threadIdx.x;
  float4 a = ((const float4*)h)[i];
  uint2 u; u.x = pk2(a.x, a.y); u.y = pk2(a.z, a.w);
  ((uint2*)xb)[i] = u;
  float4 b = ((const float4*)r)[i];
  uint2 v; v.x = pk2(b.x, b.y); v.y = pk2(b.z, b.w);
  ((uint2*)rb)[i] = v;
}

// ---------------- weight transpose+convert ----------------
struct W12 { const float* p[12]; };

__global__ void __launch_bounds__(256) k_wt(W12 srcs, bf16* __restrict__ wt_qkv,
                                            bf16* __restrict__ wt_ref, bf16* __restrict__ wt_out)
{
  int z = blockIdx.z;
  const float* src = srcs.p[z];
  float scale = (z==0 || z==3 || z==6) ? 0.125f : 1.0f;
  bf16* dst; int ldd;
  if (z < 7)      { dst = wt_qkv + (size_t)z*1280*1280; ldd = 1280; }
  else if (z < 9) { dst = wt_ref + (size_t)(z-7)*1280*1280; ldd = 1280; }
  else            { dst = wt_out + (size_t)(z-9)*1280; ldd = 3840; }

  __shared__ float tile[32][33];
  int tx = threadIdx.x & 31, ty = threadIdx.x >> 5;
  int r0 = blockIdx.y*32, c0 = blockIdx.x*32;
  #pragma unroll
  for (int i=0;i<32;i+=8)
    tile[ty+i][tx] = src[(size_t)(r0+ty+i)*1280 + c0+tx] * scale;
  __syncthreads();
  #pragma unroll
  for (int i=0;i<32;i+=8)
    dst[(size_t)(c0+ty+i)*ldd + r0+tx] = (bf16)tile[tx][ty+i];
}

// ================= 256^2 8-phase GEMM (T2+T3+T4+T5) =================
// 512 thr = 8 waves (2M x 4N), per-wave C = 128x64, BK=64, LDS 128KB dbuf.
// Quarter staging: A-X rows {0-63,128-191}, A-Y rows {64-127,192-255},
// B-X cols bit5==0, B-Y cols bit5==1. Issue order per K-tile: AX,BX,BY,AY.
// Phase p=(mq,nq) consumes {A-(mq?Y:X), B-(nq?Y:X)} -> vmcnt(4) at end of
// P0,P1,P3 certifies the next phase's quarter; P2 needs none. Never 0.

template<int MQ, int NQ>
__device__ __forceinline__ void frag_load(const char* Ab, const char* Bb,
          int wr, int wc, int c, int g, bf16x8 (&af)[4][2], bf16x8 (&bfr)[2][2])
{
  #pragma unroll
  for (int mf=0;mf<4;mf++){
    int row = wr + MQ*64 + mf*16 + c;
    #pragma unroll
    for (int kk=0;kk<2;kk++)
      af[mf][kk] = *(const bf16x8*)(Ab + row*128 + ((((kk<<2)+g)^(row&7))<<4));
  }
  #pragma unroll
  for (int nf=0;nf<2;nf++){
    int row = wc + NQ*32 + nf*16 + c;
    #pragma unroll
    for (int kk=0;kk<2;kk++)
      bfr[nf][kk] = *(const bf16x8*)(Bb + row*128 + ((((kk<<2)+g)^(row&7))<<4));
  }
}

template<int MQ, int NQ>
__device__ __forceinline__ void frag_mfma(f32x4 (&acc)[8][4], bf16x8 (&af)[4][2], bf16x8 (&bfr)[2][2])
{
  __builtin_amdgcn_s_setprio(1);
  #pragma unroll
  for (int kk=0;kk<2;kk++)
    #pragma unroll
    for (int mf=0;mf<4;mf++)
      #pragma unroll
      for (int nf=0;nf<2;nf++)
        acc[MQ*4+mf][NQ*2+nf] = __builtin_amdgcn_mfma_f32_16x16x32_bf16(
            af[mf][kk], bfr[nf][kk], acc[MQ*4+mf][NQ*2+nf], 0,0,0);
  __builtin_amdgcn_s_setprio(0);
}

#define BAR()    __builtin_amdgcn_s_barrier()
#define VMC(N)   asm volatile("s_waitcnt vmcnt(" #N ")" ::: "memory")

template<int EPI>
__global__ void __launch_bounds__(512,2) k_gemm8(const bf16* __restrict__ A, const bf16* __restrict__ BT,
            int K, int lda, int ldb,
            bf16* __restrict__ Crm, int ldc,
            bf16* __restrict__ VT1, bf16* __restrict__ VT2)
{
  __shared__ __align__(16) char lds[131072];   // A: [db][256][64], B: +65536
  const int tid = threadIdx.x;
  const int w = tid >> 6, l = tid & 63;
  const int c = l & 15, g = l >> 4;
  const int m0 = blockIdx.y * 256, n0 = blockIdx.x * 256;
  const int wr = (w >> 2) * 128, wc = (w & 3) * 64;
  const int qh = l >> 3, cc = l & 7;           // staging lane split: 8 rows x 8 chunks

  f32x4 acc[8][4];
  #pragma unroll
  for (int i=0;i<8;i++)
    #pragma unroll
    for (int j=0;j<4;j++) acc[i][j] = (f32x4){0.f,0.f,0.f,0.f};
  bf16x8 af[4][2], bfr[2][2];

  auto stA = [&](int db, int k0, int Y){       // one A quarter: 2 glds/wave
    char* base = lds + db*32768;
    #pragma unroll
    for (int i=0;i<2;i++){
      int qr0 = w*16 + i*8;
      int ar0 = (qr0 & 63) + ((qr0>>6)<<7) + (Y<<6);
      int row = ar0 + qh;
      glds16(A + (size_t)(m0+row)*lda + k0 + ((cc ^ (row&7))<<3), base + (ar0<<7));
    }
  };
  auto stB = [&](int db, int k0, int Y){
    char* base = lds + 65536 + db*32768;
    #pragma unroll
    for (int i=0;i<2;i++){
      int qr0 = w*16 + i*8;
      int br0 = (qr0 & 31) + ((qr0>>5)<<6) + (Y<<5);
      int row = br0 + qh;
      glds16(BT + (size_t)(n0+row)*ldb + k0 + ((cc ^ (row&7))<<3), base + (br0<<7));
    }
  };

  // prologue: tile 0, issue order AX,BX,BY,AY; certify AX,BX (keep 4 in flight)
  stA(0,0,0); stB(0,0,0); stB(0,0,1); stA(0,0,1);
  VMC(4);
  BAR();

  const int NT = K >> 6;
  for (int j = 0; j < NT-1; ++j){
    const int db = j & 1, k1 = (j+1) << 6;
    const char* Ab = lds + db*32768;
    const char* Bb = lds + 65536 + db*32768;
    // P0: consume AX,BX(j); issue AX(j+1); certify BY(j)
    frag_load<0,0>(Ab,Bb,wr,wc,c,g,af,bfr); stA(db^1,k1,0);
    BAR(); frag_mfma<0,0>(acc,af,bfr); VMC(4); BAR();
    // P1: consume AX,BY(j); issue BX(j+1); certify AY(j)
    frag_load<0,1>(Ab,Bb,wr,wc,c,g,af,bfr); stB(db^1,k1,0);
    BAR(); frag_mfma<0,1>(acc,af,bfr); VMC(4); BAR();
    // P2: consume AY,BX(j); issue BY(j+1); nothing new needed next
    frag_load<1,0>(Ab,Bb,wr,wc,c,g,af,bfr); stB(db^1,k1,1);
    BAR(); frag_mfma<1,0>(acc,af,bfr); BAR();
    // P3: consume AY,BY(j); issue AY(j+1); certify AX,BX(j+1)
    frag_load<1,1>(Ab,Bb,wr,wc,c,g,af,bfr); stA(db^1,k1,1);
    BAR(); frag_mfma<1,1>(acc,af,bfr); VMC(4); BAR();
  }
  { // last K-tile: drain 4 -> 2 -> 0
    const int db = (NT-1) & 1;
    const char* Ab = lds + db*32768;
    const char* Bb = lds + 65536 + db*32768;
    frag_load<0,0>(Ab,Bb,wr,wc,c,g,af,bfr); BAR(); frag_mfma<0,0>(acc,af,bfr); VMC(2); BAR();
    frag_load<0,1>(Ab,Bb,wr,wc,c,g,af,bfr); BAR(); frag_mfma<0,1>(acc,af,bfr); VMC(0); BAR();
    frag_load<1,0>(Ab,Bb,wr,wc,c,g,af,bfr); BAR(); frag_mfma<1,0>(acc,af,bfr); BAR();
    frag_load<1,1>(Ab,Bb,wr,wc,c,g,af,bfr); BAR(); frag_mfma<1,1>(acc,af,bfr);
  }

  // ---- epilogue: QKV / refKV routing (8-wave geometry) ----
  int reg = n0 / 1280;
  bool vt = (EPI==0) ? (reg==2 || reg==5) : (reg==1);
  if (!vt){
    int colbase = (EPI==0) ? (n0 - ((reg>=3)?1280:0) - ((reg>=6)?1280:0)) : n0;
    #pragma unroll
    for (int mf=0;mf<8;mf++)
      #pragma unroll
      for (int nf=0;nf<4;nf++)
        #pragma unroll
        for (int r=0;r<4;r++){
          int row = m0 + wr + mf*16 + (g<<2) + r;
          Crm[(size_t)row*ldc + colbase + wc + nf*16 + c] = (bf16)acc[mf][nf][r];
        }
  } else {
    bf16* vdst; int cm0; bool mv = false;
    if (EPI==0){
      if (reg==2){ vdst = VT1; cm0 = n0 - 2560; }
      else       { vdst = VT2; cm0 = n0 - 6400; mv = true; }
    } else       { vdst = VT1; cm0 = n0 - 1280; }
    #pragma unroll
    for (int nf=0;nf<4;nf++){
      int cm = cm0 + wc + nf*16 + c;
      int hh = cm >> 6, dd = cm & 63;
      #pragma unroll
      for (int mf=0;mf<8;mf++){
        int tok0 = m0 + wr + mf*16 + (g<<2);
        size_t addr;
        if (mv) addr = ((size_t)(hh*64 + dd))*6144 + tok0;
        else    addr = ((size_t)(((tok0>>10)*20 + hh)*64 + dd))*1024 + (size_t)(tok0 & 1023);
        uint2 v; v.x = pk2(acc[mf][nf][0], acc[mf][nf][1]); v.y = pk2(acc[mf][nf][2], acc[mf][nf][3]);
        *(uint2*)((char*)vdst + addr*2) = v;
      }
    }
  }
}

// ---------------- 128^2 GEMM (kept for the K=3840 output GEMM) ----------------
__global__ void __launch_bounds__(256) k_gemm_out(const bf16* __restrict__ A, const bf16* __restrict__ BT,
            int K, int lda, int ldb,
            const float* __restrict__ resid,
            const float* __restrict__ b0, const float* __restrict__ b1, const float* __restrict__ b2,
            float* __restrict__ outF)
{
  __shared__ bf16 As[128*64];
  __shared__ bf16 Bs[128*64];
  const int tid = threadIdx.x;
  const int w = tid >> 6, l = tid & 63;
  const int c = l & 15, g = l >> 4;
  const int m0 = blockIdx.y * 128, n0 = blockIdx.x * 128;
  const int wr = (w >> 1) * 64, wc = (w & 1) * 64;

  f32x4 acc[4][4];
  #pragma unroll
  for (int i=0;i<4;i++)
    #pragma unroll
    for (int j=0;j<4;j++) acc[i][j] = (f32x4){0.f,0.f,0.f,0.f};

  for (int k0 = 0; k0 < K; k0 += 64){
    __syncthreads();
    #pragma unroll
    for (int j=0;j<4;j++){
      int chunk = j*256 + tid;
      int row = chunk >> 3, cc = chunk & 7;
      int sc8 = ((cc ^ (row & 7)) << 3);
      glds16(A  + (size_t)(m0+row)*lda + k0 + sc8, (char*)As + ((size_t)(j*256 + (w<<6)) << 4));
      glds16(BT + (size_t)(n0+row)*ldb + k0 + sc8, (char*)Bs + ((size_t)(j*256 + (w<<6)) << 4));
    }
    __syncthreads();
    #pragma unroll
    for (int kk=0;kk<2;kk++){
      bf16x8 af[4], bfr[4];
      #pragma unroll
      for (int m=0;m<4;m++){
        int row = wr + m*16 + c;
        af[m] = *(const bf16x8*)((const char*)As + row*128 + ((((kk<<2)+g) ^ (row&7)) << 4));
      }
      #pragma unroll
      for (int n=0;n<4;n++){
        int row = wc + n*16 + c;
        bfr[n] = *(const bf16x8*)((const char*)Bs + row*128 + ((((kk<<2)+g) ^ (row&7)) << 4));
      }
      #pragma unroll
      for (int m=0;m<4;m++)
        #pragma unroll
        for (int n=0;n<4;n++)
          acc[m][n] = __builtin_amdgcn_mfma_f32_16x16x32_bf16(af[m], bfr[n], acc[m][n], 0,0,0);
    }
  }

  #pragma unroll
  for (int nf=0;nf<4;nf++){
    int col = n0 + wc + nf*16 + c;
    float bias = b0[col] + b1[col] + b2[col];
    #pragma unroll
    for (int mf=0;mf<4;mf++)
      #pragma unroll
      for (int r=0;r<4;r++){
        int row = m0 + wr + mf*16 + (g<<2) + r;
        size_t idx = (size_t)row*1280 + col;
        outF[idx] = acc[mf][nf][r] + bias + resid[idx];
      }
  }
}

// ---------------- flash attention (unchanged from R4; 869-passing) ----------------
template<int MODE>
__global__ void __launch_bounds__(256) k_flash(const bf16* __restrict__ qkv5, const bf16* __restrict__ kref,
              const bf16* __restrict__ vt_base, const bf16* __restrict__ vt_mv,
              const bf16* __restrict__ vt_ref, bf16* __restrict__ outcat)
{
  __shared__ bf16 Ks[64*64];
  __shared__ bf16 VTs[64*64];
  __shared__ bf16 Pl[128*64];
  __shared__ float scl[128];
  __shared__ float lsum[128];

  const int tid = threadIdx.x;
  const int w = tid >> 6, l = tid & 63;
  const int c = l & 15, g = l >> 4;
  const int qt = blockIdx.x, grp = blockIdx.y;

  int hh, ldk, bidx = 0, iv = 0, NKT, Lq, ocol;
  const bf16 *Qb, *Kb, *Vb;
  if (MODE==0){
    bidx = grp/20; hh = grp%20;
    Qb = qkv5 + (size_t)hh*64;
    Kb = qkv5 + 1280 + (size_t)hh*64; ldk = 6400;
    Vb = vt_base + ((size_t)(bidx*20 + hh)*64)*1024;
    NKT = 16; Lq = 1024; ocol = hh*64;
  } else if (MODE==1){
    iv = grp/20; hh = grp%20;
    Qb = qkv5 + 2560 + (size_t)hh*64;
    Kb = qkv5 + 3840 + (size_t)hh*64; ldk = 6400;
    Vb = vt_mv + ((size_t)hh*64)*6144;
    NKT = 3; Lq = 192; ocol = 1280 + hh*64;
  } else {
    bidx = grp/20; hh = grp%20;
    Qb = qkv5 + 5120 + (size_t)hh*64;
    Kb = kref + (size_t)hh*64; ldk = 1280;
    Vb = vt_ref + ((size_t)(bidx*20 + hh)*64)*1024;
    NKT = 16; Lq = 1024; ocol = 2560 + hh*64;
  }

  bf16x8 qf[2][2];
  #pragma unroll
  for (int nf=0;nf<2;nf++){
    int qa = qt*128 + w*32 + nf*16 + c;
    if (qa > Lq-1) qa = Lq-1;
    int tq = (MODE==1) ? (((qa>>5)<<10) + iv*32 + (qa&31)) : ((bidx<<10) + qa);
    #pragma unroll
    for (int kk=0;kk<2;kk++)
      qf[nf][kk] = *(const bf16x8*)(Qb + (size_t)tq*6400 + kk*32 + g*8);
  }

  float mrow[2] = {-1e30f, -1e30f};
  float lrow[2] = {0.f, 0.f};
  f32x4 oacc[2][4];
  #pragma unroll
  for (int i=0;i<2;i++)
    #pragma unroll
    for (int j=0;j<4;j++) oacc[i][j] = (f32x4){0.f,0.f,0.f,0.f};

  for (int kt=0; kt<NKT; ++kt){
    __syncthreads();
    #pragma unroll
    for (int j=0;j<2;j++){
      int lc = j*256 + tid;
      int row = lc >> 3, cc = lc & 7;
      int sc8 = ((cc ^ (row&7)) << 3);
      int ka = kt*64 + row;
      int tk = (MODE==1) ? (((ka>>5)<<10) + iv*32 + (ka&31)) : ((bidx<<10) + ka);
      glds16(Kb + (size_t)tk*ldk + sc8, (char*)Ks + ((size_t)(j*256 + (w<<6))<<4));
    }
    #pragma unroll
    for (int j=0;j<2;j++){
      int lc = j*256 + tid;
      int dd = lc >> 3, cc = lc & 7;
      int k8 = kt*64 + ((cc ^ (dd&7)) << 3);
      const bf16* src;
      if (MODE==1) src = Vb + (size_t)dd*6144 + ((k8>>5)<<10) + iv*32 + (k8&31);
      else         src = Vb + (size_t)dd*1024 + k8;
      glds16(src, (char*)VTs + ((size_t)(j*256 + (w<<6))<<4));
    }
    __syncthreads();

    f32x4 st[4][2];
    #pragma unroll
    for (int m=0;m<4;m++)
      #pragma unroll
      for (int nf=0;nf<2;nf++) st[m][nf] = (f32x4){0.f,0.f,0.f,0.f};
    #pragma unroll
    for (int kk=0;kk<2;kk++){
      bf16x8 kf[4];
      #pragma unroll
      for (int m=0;m<4;m++){
        int row = m*16 + c;
        kf[m] = *(const bf16x8*)((const char*)Ks + row*128 + ((((kk<<2)+g)^(row&7))<<4));
      }
      #pragma unroll
      for (int m=0;m<4;m++)
        #pragma unroll
        for (int nf=0;nf<2;nf++)
          st[m][nf] = __builtin_amdgcn_mfma_f32_16x16x32_bf16(kf[m], qf[nf][kk], st[m][nf], 0,0,0);
    }

    #pragma unroll
    for (int nf=0;nf<2;nf++){
      float pm = st[0][nf][0];
      #pragma unroll
      for (int m=0;m<4;m++)
        #pragma unroll
        for (int r=0;r<4;r++) pm = fmaxf(pm, st[m][nf][r]);
      pm = fmaxf(pm, __shfl_xor(pm, 16));
      pm = fmaxf(pm, __shfl_xor(pm, 32));
      float mnew = fmaxf(mrow[nf], pm);
      float sc = exp2f((mrow[nf] - mnew) * LOG2E);
      float ps = 0.f;
      int qlds = w*32 + nf*16 + c;
      #pragma unroll
      for (int m=0;m<4;m++){
        float p0 = exp2f((st[m][nf][0]-mnew)*LOG2E);
        float p1 = exp2f((st[m][nf][1]-mnew)*LOG2E);
        float p2 = exp2f((st[m][nf][2]-mnew)*LOG2E);
        float p3 = exp2f((st[m][nf][3]-mnew)*LOG2E);
        ps += p0+p1+p2+p3;
        uint2 pv; pv.x = pk2(p0,p1); pv.y = pk2(p2,p3);
        int ci = ((m*2 + (g>>1)) ^ (qlds&7));
        *(uint2*)((char*)Pl + qlds*128 + (ci<<4) + ((g&1)<<3)) = pv;
      }
      ps += __shfl_xor(ps, 16);
      ps += __shfl_xor(ps, 32);
      lrow[nf] = lrow[nf]*sc + ps;
      mrow[nf] = mnew;
      scl[qlds] = sc;
    }
    #pragma unroll
    for (int mf=0;mf<2;mf++)
      #pragma unroll
      for (int r=0;r<4;r++){
        float s = scl[w*32 + mf*16 + (g<<2) + r];
        #pragma unroll
        for (int nd=0;nd<4;nd++) oacc[mf][nd][r] *= s;
      }
    #pragma unroll
    for (int ks=0;ks<2;ks++){
      bf16x8 pf[2], vf[4];
      #pragma unroll
      for (int mf=0;mf<2;mf++){
        int q = w*32 + mf*16 + c;
        pf[mf] = *(const bf16x8*)((const char*)Pl + q*128 + ((((ks<<2)+g)^(q&7))<<4));
      }
      #pragma unroll
      for (int nd=0;nd<4;nd++){
        int row = nd*16 + c;
        vf[nd] = *(const bf16x8*)((const char*)VTs + row*128 + ((((ks<<2)+g)^(row&7))<<4));
      }
      #pragma unroll
      for (int mf=0;mf<2;mf++)
        #pragma unroll
        for (int nd=0;nd<4;nd++)
          oacc[mf][nd] = __builtin_amdgcn_mfma_f32_16x16x32_bf16(pf[mf], vf[nd], oacc[mf][nd], 0,0,0);
    }
  }

  #pragma unroll
  for (int nf=0;nf<2;nf++) lsum[w*32 + nf*16 + c] = lrow[nf];
  #pragma unroll
  for (int mf=0;mf<2;mf++)
    #pragma unroll
    for (int r=0;r<4;r++){
      int qloc = w*32 + mf*16 + (g<<2) + r;
      float inv = 1.f / lsum[qloc];
      int qa = qt*128 + qloc;
      if (qa < Lq){
        int tq = (MODE==1) ? (((qa>>5)<<10) + iv*32 + (qa&31)) : ((bidx<<10) + qa);
        #pragma unroll
        for (int nd=0;nd<4;nd++)
          outcat[(size_t)tq*3840 + ocol + nd*16 + c] = (bf16)(oacc[mf][nd][r] * inv);
      }
    }
}

// ---------------- launcher ----------------
extern "C" void kernel_launch(void* const* d_in, const int* in_sizes, int n_in,
                              void* d_out, int out_size, void* d_ws, size_t ws_size,
                              hipStream_t stream)
{
  (void)in_sizes; (void)n_in; (void)out_size; (void)ws_size;
  const float* hs  = (const float*)d_in[0];
  const float* rhs = (const float*)d_in[1];
  const float* bq  = (const float*)d_in[6];
  const float* bm  = (const float*)d_in[11];
  const float* br  = (const float*)d_in[16];

  char* ws = (char*)d_ws;
  size_t off = 0;
  auto alloc = [&](size_t bytes){ size_t a = off; off += (bytes + 255) & ~(size_t)255; return a; };
  size_t oXBF   = alloc((size_t)6144*1280*2);
  size_t oRBF   = alloc((size_t)6144*1280*2);
  size_t oWTQKV = alloc((size_t)8960*1280*2);
  size_t oWTREF = alloc((size_t)2560*1280*2);
  size_t oWTOUT = alloc((size_t)1280*3840*2);
  size_t oQKV5  = alloc((size_t)6144*6400*2);
  size_t oKREF  = alloc((size_t)6144*1280*2);
  size_t oVTB   = alloc((size_t)6*20*64*1024*2);
  size_t oVTM   = alloc((size_t)20*64*6144*2);
  size_t oVTR   = alloc((size_t)6*20*64*1024*2);
  size_t oOUT   = oXBF;   // out_cat aliases XBF+RBF+WTQKV (dead by flash time)

  bf16* XBF   = (bf16*)(ws + oXBF);
  bf16* RBF   = (bf16*)(ws + oRBF);
  bf16* WTQKV = (bf16*)(ws + oWTQKV);
  bf16* WTREF = (bf16*)(ws + oWTREF);
  bf16* WTOUT = (bf16*)(ws + oWTOUT);
  bf16* QKV5  = (bf16*)(ws + oQKV5);
  bf16* KREF  = (bf16*)(ws + oKREF);
  bf16* VTB   = (bf16*)(ws + oVTB);
  bf16* VTM   = (bf16*)(ws + oVTM);
  bf16* VTR   = (bf16*)(ws + oVTR);
  bf16* OUTC  = (bf16*)(ws + oOUT);

  k_conv<<<7680, 256, 0, stream>>>(hs, rhs, XBF, RBF);

  W12 wsrc;
  wsrc.p[0]=(const float*)d_in[2];  wsrc.p[1]=(const float*)d_in[3];  wsrc.p[2]=(const float*)d_in[4];
  wsrc.p[3]=(const float*)d_in[7];  wsrc.p[4]=(const float*)d_in[8];  wsrc.p[5]=(const float*)d_in[9];
  wsrc.p[6]=(const float*)d_in[12]; wsrc.p[7]=(const float*)d_in[13]; wsrc.p[8]=(const float*)d_in[14];
  wsrc.p[9]=(const float*)d_in[5];  wsrc.p[10]=(const float*)d_in[10]; wsrc.p[11]=(const float*)d_in[15];
  k_wt<<<dim3(40,40,12), 256, 0, stream>>>(wsrc, WTQKV, WTREF, WTOUT);

  k_gemm8<0><<<dim3(35,24), 512, 0, stream>>>(XBF, WTQKV, 1280, 1280, 1280,
      QKV5, 6400, VTB, VTM);
  k_gemm8<1><<<dim3(10,24), 512, 0, stream>>>(RBF, WTREF, 1280, 1280, 1280,
      KREF, 1280, VTR, nullptr);

  k_flash<0><<<dim3(8,120), 256, 0, stream>>>(QKV5, KREF, VTB, VTM, VTR, OUTC);
  k_flash<1><<<dim3(2,640), 256, 0, stream>>>(QKV5, KREF, VTB, VTM, VTR, OUTC);
  k_flash<2><<<dim3(8,120), 256, 0, stream>>>(QKV5, KREF, VTB, VTM, VTR, OUTC);

  k_gemm_out<<<dim3(10,48), 256, 0, stream>>>(OUTC, WTOUT, 3840, 3840, 3840,
      hs, bq, bm, br, (float*)d_out);
}

// Round 8
// 695.932 us; speedup vs baseline: 1.0446x; 1.0264x over previous
//
#include <hip/hip_runtime.h>
#include <hip/hip_bf16.h>

// DecoupledMVRowSelfAttn, round 8 (identical resubmit of R7; R6/R7 were
// broker acquisition timeouts — the fragment-reuse GEMM has never run).
// R5 post-mortem: 256^2 8-phase GEMM at 190us / MfmaUtil 31% because frag_load
// re-read A+B fragments EVERY phase (48 ds_read_b128/K-tile vs 24 min) ->
// LDS-read critical path. This version: fragment reuse (12/4/8/0 reads across
// the 4 phases), XCD chunked swizzle, and barriers after the last tile's
// vmcnt waits (per-wave vmcnt + s_barrier = all-waves-landed protocol).

typedef __bf16 bf16;
typedef __bf16 bf16x8 __attribute__((ext_vector_type(8)));
typedef float f32x4 __attribute__((ext_vector_type(4)));

#define LOG2E 1.44269504088896340f

__device__ __forceinline__ unsigned pk2(float a, float b){
  unsigned short x = __builtin_bit_cast(unsigned short, (bf16)a);
  unsigned short y = __builtin_bit_cast(unsigned short, (bf16)b);
  return (unsigned)x | ((unsigned)y << 16);
}

__device__ __forceinline__ void glds16(const void* g, void* l){
  __builtin_amdgcn_global_load_lds((const __attribute__((address_space(1))) void*)g,
                                   (__attribute__((address_space(3))) void*)l, 16, 0, 0);
}

// ---------------- convert hidden/ref to bf16 ----------------
__global__ void __launch_bounds__(256) k_conv(const float* __restrict__ h,
                                              const float* __restrict__ r,
                                              bf16* __restrict__ xb, bf16* __restrict__ rb)
{
  size_t i = (size_t)blockIdx.x*256 + threadIdx.x;
  float4 a = ((const float4*)h)[i];
  uint2 u; u.x = pk2(a.x, a.y); u.y = pk2(a.z, a.w);
  ((uint2*)xb)[i] = u;
  float4 b = ((const float4*)r)[i];
  uint2 v; v.x = pk2(b.x, b.y); v.y = pk2(b.z, b.w);
  ((uint2*)rb)[i] = v;
}

// ---------------- weight transpose+convert ----------------
struct W12 { const float* p[12]; };

__global__ void __launch_bounds__(256) k_wt(W12 srcs, bf16* __restrict__ wt_qkv,
                                            bf16* __restrict__ wt_ref, bf16* __restrict__ wt_out)
{
  int z = blockIdx.z;
  const float* src = srcs.p[z];
  float scale = (z==0 || z==3 || z==6) ? 0.125f : 1.0f;
  bf16* dst; int ldd;
  if (z < 7)      { dst = wt_qkv + (size_t)z*1280*1280; ldd = 1280; }
  else if (z < 9) { dst = wt_ref + (size_t)(z-7)*1280*1280; ldd = 1280; }
  else            { dst = wt_out + (size_t)(z-9)*1280; ldd = 3840; }

  __shared__ float tile[32][33];
  int tx = threadIdx.x & 31, ty = threadIdx.x >> 5;
  int r0 = blockIdx.y*32, c0 = blockIdx.x*32;
  #pragma unroll
  for (int i=0;i<32;i+=8)
    tile[ty+i][tx] = src[(size_t)(r0+ty+i)*1280 + c0+tx] * scale;
  __syncthreads();
  #pragma unroll
  for (int i=0;i<32;i+=8)
    dst[(size_t)(c0+ty+i)*ldd + r0+tx] = (bf16)tile[tx][ty+i];
}

// ================= 256^2 8-phase GEMM, fragment-reuse =================
// 512 thr = 8 waves (2M x 4N), per-wave C = 128x64, BK=64, LDS 128KB dbuf.
// Quarters (consumption-aligned): A-X rows {0-63,128-191}, A-Y {64-127,192-255},
// B-X cols bit5==0, B-Y bit5==1. Stage order per K-tile: AX,BX,BY,AY.
// ds_reads: 12/4/8/0 across phases (each fragment once per K-tile).
// vmcnt(4) at P0,P1,P3 + barrier certifies the quarter the next phase reads.

template<int MQ>
__device__ __forceinline__ void ldA(const char* Ab, int wr, int c, int g, bf16x8 (&a)[8]){
  #pragma unroll
  for (int mf=0;mf<4;mf++){
    int row = wr + MQ*64 + mf*16 + c;
    #pragma unroll
    for (int kk=0;kk<2;kk++)
      a[mf*2+kk] = *(const bf16x8*)(Ab + row*128 + ((((kk<<2)+g)^(row&7))<<4));
  }
}
template<int NQ>
__device__ __forceinline__ void ldB(const char* Bb, int wc, int c, int g, bf16x8 (&b)[4]){
  #pragma unroll
  for (int nf=0;nf<2;nf++){
    int row = wc + NQ*32 + nf*16 + c;
    #pragma unroll
    for (int kk=0;kk<2;kk++)
      b[nf*2+kk] = *(const bf16x8*)(Bb + row*128 + ((((kk<<2)+g)^(row&7))<<4));
  }
}
template<int MQ,int NQ>
__device__ __forceinline__ void mfma8(f32x4 (&acc)[8][4], bf16x8 (&a)[8], bf16x8 (&b)[4]){
  __builtin_amdgcn_s_setprio(1);
  #pragma unroll
  for (int kk=0;kk<2;kk++)
    #pragma unroll
    for (int mf=0;mf<4;mf++)
      #pragma unroll
      for (int nf=0;nf<2;nf++)
        acc[MQ*4+mf][NQ*2+nf] = __builtin_amdgcn_mfma_f32_16x16x32_bf16(
            a[mf*2+kk], b[nf*2+kk], acc[MQ*4+mf][NQ*2+nf], 0,0,0);
  __builtin_amdgcn_s_setprio(0);
}

#define BAR()    __builtin_amdgcn_s_barrier()
#define VMC(N)   asm volatile("s_waitcnt vmcnt(" #N ")" ::: "memory")

template<int EPI>
__global__ void __launch_bounds__(512,2) k_gemm8(const bf16* __restrict__ A, const bf16* __restrict__ BT,
            int K, int lda, int ldb,
            bf16* __restrict__ Crm, int ldc,
            bf16* __restrict__ VT1, bf16* __restrict__ VT2)
{
  __shared__ __align__(16) char lds[131072];   // A: [db][256][64], B: +65536
  const int tid = threadIdx.x;
  const int w = tid >> 6, l = tid & 63;
  const int c = l & 15, g = l >> 4;

  // T1: bijective XCD chunked swizzle (nwg % 8 == 0 for all our grids)
  int nwg = gridDim.x * gridDim.y;
  int bid = blockIdx.y * gridDim.x + blockIdx.x;
  int swz = (bid & 7) * (nwg >> 3) + (bid >> 3);
  int bx = swz % gridDim.x, by = swz / gridDim.x;
  const int m0 = by * 256, n0 = bx * 256;

  const int wr = (w >> 2) * 128, wc = (w & 3) * 64;
  const int qh = l >> 3, cc = l & 7;

  f32x4 acc[8][4];
  #pragma unroll
  for (int i=0;i<8;i++)
    #pragma unroll
    for (int j=0;j<4;j++) acc[i][j] = (f32x4){0.f,0.f,0.f,0.f};
  bf16x8 a0[8], a1[8], b0[4], b1[4];

  auto stA = [&](int db, int k0, int Y){       // one A quarter: 2 glds/wave
    char* base = lds + db*32768;
    #pragma unroll
    for (int i=0;i<2;i++){
      int qr0 = w*16 + i*8;
      int ar0 = (qr0 & 63) + ((qr0>>6)<<7) + (Y<<6);
      int row = ar0 + qh;
      glds16(A + (size_t)(m0+row)*lda + k0 + ((cc ^ (row&7))<<3), base + (ar0<<7));
    }
  };
  auto stB = [&](int db, int k0, int Y){
    char* base = lds + 65536 + db*32768;
    #pragma unroll
    for (int i=0;i<2;i++){
      int qr0 = w*16 + i*8;
      int br0 = (qr0 & 31) + ((qr0>>5)<<6) + (Y<<5);
      int row = br0 + qh;
      glds16(BT + (size_t)(n0+row)*ldb + k0 + ((cc ^ (row&7))<<3), base + (br0<<7));
    }
  };

  // prologue: tile 0 (AX,BX,BY,AY); certify AX,BX, keep BY,AY in flight
  stA(0,0,0); stB(0,0,0); stB(0,0,1); stA(0,0,1);
  VMC(4);
  BAR();

  const int NT = K >> 6;
  for (int j = 0; j < NT-1; ++j){
    const int db = j & 1, k1 = (j+1) << 6;
    const char* Ab = lds + db*32768;
    const char* Bb = lds + 65536 + db*32768;
    // P0: ds 12 (A0,B0); issue AX(j+1); mfma(0,0); certify BY(j)
    ldA<0>(Ab,wr,c,g,a0); ldB<0>(Bb,wc,c,g,b0); stA(db^1,k1,0);
    BAR(); mfma8<0,0>(acc,a0,b0); VMC(4); BAR();
    // P1: ds 4 (B1); issue BX(j+1); mfma(0,1); certify AY(j)
    ldB<1>(Bb,wc,c,g,b1); stB(db^1,k1,0);
    BAR(); mfma8<0,1>(acc,a0,b1); VMC(4); BAR();
    // P2: ds 8 (A1); issue BY(j+1); mfma(1,0)
    ldA<1>(Ab,wr,c,g,a1); stB(db^1,k1,1);
    BAR(); mfma8<1,0>(acc,a1,b0); BAR();
    // P3: ds 0; issue AY(j+1); mfma(1,1); certify AX,BX(j+1)
    stA(db^1,k1,1);
    BAR(); mfma8<1,1>(acc,a1,b1); VMC(4); BAR();
  }
  { // last K-tile: drain 4 -> 2 -> 0. Each VMC certifies only THIS wave's
    // loads; the following BAR makes it an all-waves-landed guarantee.
    const int db = (NT-1) & 1;
    const char* Ab = lds + db*32768;
    const char* Bb = lds + 65536 + db*32768;
    ldA<0>(Ab,wr,c,g,a0); ldB<0>(Bb,wc,c,g,b0);
    mfma8<0,0>(acc,a0,b0);
    VMC(2); BAR();
    ldB<1>(Bb,wc,c,g,b1);
    mfma8<0,1>(acc,a0,b1);
    VMC(0); BAR();
    ldA<1>(Ab,wr,c,g,a1);
    mfma8<1,0>(acc,a1,b0);
    mfma8<1,1>(acc,a1,b1);
  }

  // ---- epilogue: QKV / refKV routing ----
  int reg = n0 / 1280;
  bool vt = (EPI==0) ? (reg==2 || reg==5) : (reg==1);
  if (!vt){
    int colbase = (EPI==0) ? (n0 - ((reg>=3)?1280:0) - ((reg>=6)?1280:0)) : n0;
    #pragma unroll
    for (int mf=0;mf<8;mf++)
      #pragma unroll
      for (int nf=0;nf<4;nf++)
        #pragma unroll
        for (int r=0;r<4;r++){
          int row = m0 + wr + mf*16 + (g<<2) + r;
          Crm[(size_t)row*ldc + colbase + wc + nf*16 + c] = (bf16)acc[mf][nf][r];
        }
  } else {
    bf16* vdst; int cm0; bool mv = false;
    if (EPI==0){
      if (reg==2){ vdst = VT1; cm0 = n0 - 2560; }
      else       { vdst = VT2; cm0 = n0 - 6400; mv = true; }
    } else       { vdst = VT1; cm0 = n0 - 1280; }
    #pragma unroll
    for (int nf=0;nf<4;nf++){
      int cm = cm0 + wc + nf*16 + c;
      int hh = cm >> 6, dd = cm & 63;
      #pragma unroll
      for (int mf=0;mf<8;mf++){
        int tok0 = m0 + wr + mf*16 + (g<<2);
        size_t addr;
        if (mv) addr = ((size_t)(hh*64 + dd))*6144 + tok0;
        else    addr = ((size_t)(((tok0>>10)*20 + hh)*64 + dd))*1024 + (size_t)(tok0 & 1023);
        uint2 v; v.x = pk2(acc[mf][nf][0], acc[mf][nf][1]); v.y = pk2(acc[mf][nf][2], acc[mf][nf][3]);
        *(uint2*)((char*)vdst + addr*2) = v;
      }
    }
  }
}

// ---------------- 128^2 GEMM (K=3840 output GEMM) ----------------
__global__ void __launch_bounds__(256) k_gemm_out(const bf16* __restrict__ A, const bf16* __restrict__ BT,
            int K, int lda, int ldb,
            const float* __restrict__ resid,
            const float* __restrict__ b0, const float* __restrict__ b1, const float* __restrict__ b2,
            float* __restrict__ outF)
{
  __shared__ bf16 As[128*64];
  __shared__ bf16 Bs[128*64];
  const int tid = threadIdx.x;
  const int w = tid >> 6, l = tid & 63;
  const int c = l & 15, g = l >> 4;
  const int m0 = blockIdx.y * 128, n0 = blockIdx.x * 128;
  const int wr = (w >> 1) * 64, wc = (w & 1) * 64;

  f32x4 acc[4][4];
  #pragma unroll
  for (int i=0;i<4;i++)
    #pragma unroll
    for (int j=0;j<4;j++) acc[i][j] = (f32x4){0.f,0.f,0.f,0.f};

  for (int k0 = 0; k0 < K; k0 += 64){
    __syncthreads();
    #pragma unroll
    for (int j=0;j<4;j++){
      int chunk = j*256 + tid;
      int row = chunk >> 3, cc = chunk & 7;
      int sc8 = ((cc ^ (row & 7)) << 3);
      glds16(A  + (size_t)(m0+row)*lda + k0 + sc8, (char*)As + ((size_t)(j*256 + (w<<6)) << 4));
      glds16(BT + (size_t)(n0+row)*ldb + k0 + sc8, (char*)Bs + ((size_t)(j*256 + (w<<6)) << 4));
    }
    __syncthreads();
    #pragma unroll
    for (int kk=0;kk<2;kk++){
      bf16x8 af[4], bfr[4];
      #pragma unroll
      for (int m=0;m<4;m++){
        int row = wr + m*16 + c;
        af[m] = *(const bf16x8*)((const char*)As + row*128 + ((((kk<<2)+g) ^ (row&7)) << 4));
      }
      #pragma unroll
      for (int n=0;n<4;n++){
        int row = wc + n*16 + c;
        bfr[n] = *(const bf16x8*)((const char*)Bs + row*128 + ((((kk<<2)+g) ^ (row&7)) << 4));
      }
      #pragma unroll
      for (int m=0;m<4;m++)
        #pragma unroll
        for (int n=0;n<4;n++)
          acc[m][n] = __builtin_amdgcn_mfma_f32_16x16x32_bf16(af[m], bfr[n], acc[m][n], 0,0,0);
    }
  }

  #pragma unroll
  for (int nf=0;nf<4;nf++){
    int col = n0 + wc + nf*16 + c;
    float bias = b0[col] + b1[col] + b2[col];
    #pragma unroll
    for (int mf=0;mf<4;mf++)
      #pragma unroll
      for (int r=0;r<4;r++){
        int row = m0 + wr + mf*16 + (g<<2) + r;
        size_t idx = (size_t)row*1280 + col;
        outF[idx] = acc[mf][nf][r] + bias + resid[idx];
      }
  }
}

// ---------------- flash attention (frozen from R4) ----------------
template<int MODE>
__global__ void __launch_bounds__(256) k_flash(const bf16* __restrict__ qkv5, const bf16* __restrict__ kref,
              const bf16* __restrict__ vt_base, const bf16* __restrict__ vt_mv,
              const bf16* __restrict__ vt_ref, bf16* __restrict__ outcat)
{
  __shared__ bf16 Ks[64*64];
  __shared__ bf16 VTs[64*64];
  __shared__ bf16 Pl[128*64];
  __shared__ float scl[128];
  __shared__ float lsum[128];

  const int tid = threadIdx.x;
  const int w = tid >> 6, l = tid & 63;
  const int c = l & 15, g = l >> 4;
  const int qt = blockIdx.x, grp = blockIdx.y;

  int hh, ldk, bidx = 0, iv = 0, NKT, Lq, ocol;
  const bf16 *Qb, *Kb, *Vb;
  if (MODE==0){
    bidx = grp/20; hh = grp%20;
    Qb = qkv5 + (size_t)hh*64;
    Kb = qkv5 + 1280 + (size_t)hh*64; ldk = 6400;
    Vb = vt_base + ((size_t)(bidx*20 + hh)*64)*1024;
    NKT = 16; Lq = 1024; ocol = hh*64;
  } else if (MODE==1){
    iv = grp/20; hh = grp%20;
    Qb = qkv5 + 2560 + (size_t)hh*64;
    Kb = qkv5 + 3840 + (size_t)hh*64; ldk = 6400;
    Vb = vt_mv + ((size_t)hh*64)*6144;
    NKT = 3; Lq = 192; ocol = 1280 + hh*64;
  } else {
    bidx = grp/20; hh = grp%20;
    Qb = qkv5 + 5120 + (size_t)hh*64;
    Kb = kref + (size_t)hh*64; ldk = 1280;
    Vb = vt_ref + ((size_t)(bidx*20 + hh)*64)*1024;
    NKT = 16; Lq = 1024; ocol = 2560 + hh*64;
  }

  bf16x8 qf[2][2];
  #pragma unroll
  for (int nf=0;nf<2;nf++){
    int qa = qt*128 + w*32 + nf*16 + c;
    if (qa > Lq-1) qa = Lq-1;
    int tq = (MODE==1) ? (((qa>>5)<<10) + iv*32 + (qa&31)) : ((bidx<<10) + qa);
    #pragma unroll
    for (int kk=0;kk<2;kk++)
      qf[nf][kk] = *(const bf16x8*)(Qb + (size_t)tq*6400 + kk*32 + g*8);
  }

  float mrow[2] = {-1e30f, -1e30f};
  float lrow[2] = {0.f, 0.f};
  f32x4 oacc[2][4];
  #pragma unroll
  for (int i=0;i<2;i++)
    #pragma unroll
    for (int j=0;j<4;j++) oacc[i][j] = (f32x4){0.f,0.f,0.f,0.f};

  for (int kt=0; kt<NKT; ++kt){
    __syncthreads();
    #pragma unroll
    for (int j=0;j<2;j++){
      int lc = j*256 + tid;
      int row = lc >> 3, cc = lc & 7;
      int sc8 = ((cc ^ (row&7)) << 3);
      int ka = kt*64 + row;
      int tk = (MODE==1) ? (((ka>>5)<<10) + iv*32 + (ka&31)) : ((bidx<<10) + ka);
      glds16(Kb + (size_t)tk*ldk + sc8, (char*)Ks + ((size_t)(j*256 + (w<<6))<<4));
    }
    #pragma unroll
    for (int j=0;j<2;j++){
      int lc = j*256 + tid;
      int dd = lc >> 3, cc = lc & 7;
      int k8 = kt*64 + ((cc ^ (dd&7)) << 3);
      const bf16* src;
      if (MODE==1) src = Vb + (size_t)dd*6144 + ((k8>>5)<<10) + iv*32 + (k8&31);
      else         src = Vb + (size_t)dd*1024 + k8;
      glds16(src, (char*)VTs + ((size_t)(j*256 + (w<<6))<<4));
    }
    __syncthreads();

    f32x4 st[4][2];
    #pragma unroll
    for (int m=0;m<4;m++)
      #pragma unroll
      for (int nf=0;nf<2;nf++) st[m][nf] = (f32x4){0.f,0.f,0.f,0.f};
    #pragma unroll
    for (int kk=0;kk<2;kk++){
      bf16x8 kf[4];
      #pragma unroll
      for (int m=0;m<4;m++){
        int row = m*16 + c;
        kf[m] = *(const bf16x8*)((const char*)Ks + row*128 + ((((kk<<2)+g)^(row&7))<<4));
      }
      #pragma unroll
      for (int m=0;m<4;m++)
        #pragma unroll
        for (int nf=0;nf<2;nf++)
          st[m][nf] = __builtin_amdgcn_mfma_f32_16x16x32_bf16(kf[m], qf[nf][kk], st[m][nf], 0,0,0);
    }

    #pragma unroll
    for (int nf=0;nf<2;nf++){
      float pm = st[0][nf][0];
      #pragma unroll
      for (int m=0;m<4;m++)
        #pragma unroll
        for (int r=0;r<4;r++) pm = fmaxf(pm, st[m][nf][r]);
      pm = fmaxf(pm, __shfl_xor(pm, 16));
      pm = fmaxf(pm, __shfl_xor(pm, 32));
      float mnew = fmaxf(mrow[nf], pm);
      float sc = exp2f((mrow[nf] - mnew) * LOG2E);
      float ps = 0.f;
      int qlds = w*32 + nf*16 + c;
      #pragma unroll
      for (int m=0;m<4;m++){
        float p0 = exp2f((st[m][nf][0]-mnew)*LOG2E);
        float p1 = exp2f((st[m][nf][1]-mnew)*LOG2E);
        float p2 = exp2f((st[m][nf][2]-mnew)*LOG2E);
        float p3 = exp2f((st[m][nf][3]-mnew)*LOG2E);
        ps += p0+p1+p2+p3;
        uint2 pv; pv.x = pk2(p0,p1); pv.y = pk2(p2,p3);
        int ci = ((m*2 + (g>>1)) ^ (qlds&7));
        *(uint2*)((char*)Pl + qlds*128 + (ci<<4) + ((g&1)<<3)) = pv;
      }
      ps += __shfl_xor(ps, 16);
      ps += __shfl_xor(ps, 32);
      lrow[nf] = lrow[nf]*sc + ps;
      mrow[nf] = mnew;
      scl[qlds] = sc;
    }
    #pragma unroll
    for (int mf=0;mf<2;mf++)
      #pragma unroll
      for (int r=0;r<4;r++){
        float s = scl[w*32 + mf*16 + (g<<2) + r];
        #pragma unroll
        for (int nd=0;nd<4;nd++) oacc[mf][nd][r] *= s;
      }
    #pragma unroll
    for (int ks=0;ks<2;ks++){
      bf16x8 pf[2], vf[4];
      #pragma unroll
      for (int mf=0;mf<2;mf++){
        int q = w*32 + mf*16 + c;
        pf[mf] = *(const bf16x8*)((const char*)Pl + q*128 + ((((ks<<2)+g)^(q&7))<<4));
      }
      #pragma unroll
      for (int nd=0;nd<4;nd++){
        int row = nd*16 + c;
        vf[nd] = *(const bf16x8*)((const char*)VTs + row*128 + ((((ks<<2)+g)^(row&7))<<4));
      }
      #pragma unroll
      for (int mf=0;mf<2;mf++)
        #pragma unroll
        for (int nd=0;nd<4;nd++)
          oacc[mf][nd] = __builtin_amdgcn_mfma_f32_16x16x32_bf16(pf[mf], vf[nd], oacc[mf][nd], 0,0,0);
    }
  }

  #pragma unroll
  for (int nf=0;nf<2;nf++) lsum[w*32 + nf*16 + c] = lrow[nf];
  #pragma unroll
  for (int mf=0;mf<2;mf++)
    #pragma unroll
    for (int r=0;r<4;r++){
      int qloc = w*32 + mf*16 + (g<<2) + r;
      float inv = 1.f / lsum[qloc];
      int qa = qt*128 + qloc;
      if (qa < Lq){
        int tq = (MODE==1) ? (((qa>>5)<<10) + iv*32 + (qa&31)) : ((bidx<<10) + qa);
        #pragma unroll
        for (int nd=0;nd<4;nd++)
          outcat[(size_t)tq*3840 + ocol + nd*16 + c] = (bf16)(oacc[mf][nd][r] * inv);
      }
    }
}

// ---------------- launcher ----------------
extern "C" void kernel_launch(void* const* d_in, const int* in_sizes, int n_in,
                              void* d_out, int out_size, void* d_ws, size_t ws_size,
                              hipStream_t stream)
{
  (void)in_sizes; (void)n_in; (void)out_size; (void)ws_size;
  const float* hs  = (const float*)d_in[0];
  const float* rhs = (const float*)d_in[1];
  const float* bq  = (const float*)d_in[6];
  const float* bm  = (const float*)d_in[11];
  const float* br  = (const float*)d_in[16];

  char* ws = (char*)d_ws;
  size_t off = 0;
  auto alloc = [&](size_t bytes){ size_t a = off; off += (bytes + 255) & ~(size_t)255; return a; };
  size_t oXBF   = alloc((size_t)6144*1280*2);
  size_t oRBF   = alloc((size_t)6144*1280*2);
  size_t oWTQKV = alloc((size_t)8960*1280*2);
  size_t oWTREF = alloc((size_t)2560*1280*2);
  size_t oWTOUT = alloc((size_t)1280*3840*2);
  size_t oQKV5  = alloc((size_t)6144*6400*2);
  size_t oKREF  = alloc((size_t)6144*1280*2);
  size_t oVTB   = alloc((size_t)6*20*64*1024*2);
  size_t oVTM   = alloc((size_t)20*64*6144*2);
  size_t oVTR   = alloc((size_t)6*20*64*1024*2);
  size_t oOUT   = oXBF;   // out_cat aliases XBF+RBF+WTQKV (dead by flash time)

  bf16* XBF   = (bf16*)(ws + oXBF);
  bf16* RBF   = (bf16*)(ws + oRBF);
  bf16* WTQKV = (bf16*)(ws + oWTQKV);
  bf16* WTREF = (bf16*)(ws + oWTREF);
  bf16* WTOUT = (bf16*)(ws + oWTOUT);
  bf16* QKV5  = (bf16*)(ws + oQKV5);
  bf16* KREF  = (bf16*)(ws + oKREF);
  bf16* VTB   = (bf16*)(ws + oVTB);
  bf16* VTM   = (bf16*)(ws + oVTM);
  bf16* VTR   = (bf16*)(ws + oVTR);
  bf16* OUTC  = (bf16*)(ws + oOUT);

  k_conv<<<7680, 256, 0, stream>>>(hs, rhs, XBF, RBF);

  W12 wsrc;
  wsrc.p[0]=(const float*)d_in[2];  wsrc.p[1]=(const float*)d_in[3];  wsrc.p[2]=(const float*)d_in[4];
  wsrc.p[3]=(const float*)d_in[7];  wsrc.p[4]=(const float*)d_in[8];  wsrc.p[5]=(const float*)d_in[9];
  wsrc.p[6]=(const float*)d_in[12]; wsrc.p[7]=(const float*)d_in[13]; wsrc.p[8]=(const float*)d_in[14];
  wsrc.p[9]=(const float*)d_in[5];  wsrc.p[10]=(const float*)d_in[10]; wsrc.p[11]=(const float*)d_in[15];
  k_wt<<<dim3(40,40,12), 256, 0, stream>>>(wsrc, WTQKV, WTREF, WTOUT);

  k_gemm8<0><<<dim3(35,24), 512, 0, stream>>>(XBF, WTQKV, 1280, 1280, 1280,
      QKV5, 6400, VTB, VTM);
  k_gemm8<1><<<dim3(10,24), 512, 0, stream>>>(RBF, WTREF, 1280, 1280, 1280,
      KREF, 1280, VTR, nullptr);

  k_flash<0><<<dim3(8,120), 256, 0, stream>>>(QKV5, KREF, VTB, VTM, VTR, OUTC);
  k_flash<1><<<dim3(2,640), 256, 0, stream>>>(QKV5, KREF, VTB, VTM, VTR, OUTC);
  k_flash<2><<<dim3(8,120), 256, 0, stream>>>(QKV5, KREF, VTB, VTM, VTR, OUTC);

  k_gemm_out<<<dim3(10,48), 256, 0, stream>>>(OUTC, WTOUT, 3840, 3840, 3840,
      hs, bq, bm, br, (float*)d_out);
}